// Round 5
// baseline (1198.892 us; speedup 1.0000x reference)
//
#include <hip/hip_runtime.h>

#define N_ROWS 131072
#define KCODES 1024
#define DIM 64
#define BLOCK 256
#define ROWS_PER_BLOCK 64

// h: [32, 64, 64, 64] fp32 (B, D, H, W) -> row n = b*4096 + y*64 + x reads h[b][d][y][x]
// codebook: [1024, 64] fp32
// out: [131072] z-as-float ++ [131072*64] q fp32
// d_ws: c2[1024] fp32

// ---- kernel 1: c2[k] = ||codebook[k]||^2, numpy-pairwise order ----
__global__ void c2_kernel(const float* __restrict__ cb, float* __restrict__ c2)
{
#pragma clang fp contract(off)
    const int k = blockIdx.x * 256 + threadIdx.x;
    const float* c = cb + k * DIM;
    float r0 = c[0]*c[0], r1 = c[1]*c[1], r2 = c[2]*c[2], r3 = c[3]*c[3];
    float r4 = c[4]*c[4], r5 = c[5]*c[5], r6 = c[6]*c[6], r7 = c[7]*c[7];
#pragma unroll
    for (int i = 1; i < 8; ++i) {
        r0 = r0 + c[i*8+0]*c[i*8+0];
        r1 = r1 + c[i*8+1]*c[i*8+1];
        r2 = r2 + c[i*8+2]*c[i*8+2];
        r3 = r3 + c[i*8+3]*c[i*8+3];
        r4 = r4 + c[i*8+4]*c[i*8+4];
        r5 = r5 + c[i*8+5]*c[i*8+5];
        r6 = r6 + c[i*8+6]*c[i*8+6];
        r7 = r7 + c[i*8+7]*c[i*8+7];
    }
    c2[k] = ((r0 + r1) + (r2 + r3)) + ((r4 + r5) + (r6 + r7));
}

// ---- kernel 2: split-K argmin. Block = 4 waves x same 64 rows, disjoint 256-code segs ----
__global__ void
__attribute__((amdgpu_flat_work_group_size(256, 256), amdgpu_waves_per_eu(4, 8)))
vq_argmin_kernel(
    const float* __restrict__ h,
    const float* __restrict__ cb,
    const float* __restrict__ c2g,
    float* __restrict__ z_out,
    float* __restrict__ q_out)
{
    __shared__ float s_c2[KCODES];
    __shared__ float s_bd[4 * ROWS_PER_BLOCK];
    __shared__ int   s_bk[4 * ROWS_PER_BLOCK];
    __shared__ int   s_idx[ROWS_PER_BLOCK];

    const int tid  = threadIdx.x;
    const int wave = tid >> 6;        // 0..3 -> code segment
    const int lane = tid & 63;        // row within block
    const int row  = blockIdx.x * ROWS_PER_BLOCK + lane;

    // c2 -> LDS, coalesced
#pragma unroll
    for (int i = 0; i < KCODES / BLOCK; ++i)
        s_c2[i * BLOCK + tid] = c2g[i * BLOCK + tid];
    __syncthreads();

    // ---- this wave's copy of row x: 16 float4 pinned to VGPRs ----
    const int b  = row >> 12;
    const int yx = row & 4095;
    const float* hp = h + (size_t)b * (DIM * 4096) + yx;

#define LD(d) hp[(size_t)(d) * 4096]
#define XDECL(n) float4 x##n = make_float4(LD(4*(n)+0), LD(4*(n)+1), LD(4*(n)+2), LD(4*(n)+3)); \
    asm("" : "+v"(x##n.x), "+v"(x##n.y), "+v"(x##n.z), "+v"(x##n.w));
    XDECL(0)  XDECL(1)  XDECL(2)  XDECL(3)
    XDECL(4)  XDECL(5)  XDECL(6)  XDECL(7)
    XDECL(8)  XDECL(9)  XDECL(10) XDECL(11)
    XDECL(12) XDECL(13) XDECL(14) XDECL(15)
#undef XDECL
#undef LD

    // ---- S = ||x||^2, numpy pairwise (identical in all 4 waves) ----
    float S;
    {
#pragma clang fp contract(off)
        float r0 = x0.x*x0.x, r1 = x0.y*x0.y, r2 = x0.z*x0.z, r3 = x0.w*x0.w;
        float r4 = x1.x*x1.x, r5 = x1.y*x1.y, r6 = x1.z*x1.z, r7 = x1.w*x1.w;
#define SQACC(ve, vo) \
        r0 = r0 + ve.x*ve.x; r1 = r1 + ve.y*ve.y; r2 = r2 + ve.z*ve.z; r3 = r3 + ve.w*ve.w; \
        r4 = r4 + vo.x*vo.x; r5 = r5 + vo.y*vo.y; r6 = r6 + vo.z*vo.z; r7 = r7 + vo.w*vo.w;
        SQACC(x2,  x3)  SQACC(x4,  x5)  SQACC(x6,  x7)
        SQACC(x8,  x9)  SQACC(x10, x11) SQACC(x12, x13)
        SQACC(x14, x15)
#undef SQACC
        S = ((r0 + r1) + (r2 + r3)) + ((r4 + r5) + (r6 + r7));
    }

    // ---- segment scan: 256 codes, 2 per iter, sequential FMA chains (bit-exact d2) ----
    const int k0 = wave << 8;
    float best_d = 3.4e38f;
    int   best_k = k0;

#define DOT4(v, base) \
        a0 = __builtin_fmaf(v.x, c0[(base)+0], a0); a1 = __builtin_fmaf(v.x, c1[(base)+0], a1); \
        a0 = __builtin_fmaf(v.y, c0[(base)+1], a0); a1 = __builtin_fmaf(v.y, c1[(base)+1], a1); \
        a0 = __builtin_fmaf(v.z, c0[(base)+2], a0); a1 = __builtin_fmaf(v.z, c1[(base)+2], a1); \
        a0 = __builtin_fmaf(v.w, c0[(base)+3], a0); a1 = __builtin_fmaf(v.w, c1[(base)+3], a1);

    for (int k = k0; k < k0 + 256; k += 2) {
        const float* c0 = cb + (k << 6);   // wave-uniform -> s_load stream
        const float* c1 = c0 + DIM;
        float a0 = 0.0f, a1 = 0.0f;
        DOT4(x0,  0)  DOT4(x1,  4)  DOT4(x2,  8)  DOT4(x3,  12)
        DOT4(x4,  16) DOT4(x5,  20) DOT4(x6,  24) DOT4(x7,  28)
        DOT4(x8,  32) DOT4(x9,  36) DOT4(x10, 40) DOT4(x11, 44)
        DOT4(x12, 48) DOT4(x13, 52) DOT4(x14, 56) DOT4(x15, 60)

        float d2a, d2b;
        {
#pragma clang fp contract(off)
            float ta = 2.0f * a0;     // exact
            float tb = 2.0f * a1;
            float ua = S - ta;        // rounded like np
            float ub = S - tb;
            d2a = ua + s_c2[k];
            d2b = ub + s_c2[k + 1];
        }
        if (d2a < best_d) { best_d = d2a; best_k = k; }
        if (d2b < best_d) { best_d = d2b; best_k = k + 1; }
    }
#undef DOT4

    s_bd[wave * ROWS_PER_BLOCK + lane] = best_d;
    s_bk[wave * ROWS_PER_BLOCK + lane] = best_k;
    __syncthreads();

    // ---- combine 4 segments in wave order (strict < keeps lowest segment on ties,
    //      matching np.argmin first-index; d2 bits identical to full-scan version) ----
    if (tid < ROWS_PER_BLOCK) {
        float bd = s_bd[tid];
        int   bk = s_bk[tid];
#pragma unroll
        for (int w = 1; w < 4; ++w) {
            float d = s_bd[w * ROWS_PER_BLOCK + tid];
            int   kk = s_bk[w * ROWS_PER_BLOCK + tid];
            if (d < bd) { bd = d; bk = kk; }
        }
        z_out[blockIdx.x * ROWS_PER_BLOCK + tid] = (float)bk;
        s_idx[tid] = bk;
    }
    __syncthreads();

    // ---- q gather: 64 rows x 16 float4 = 1024 stores over 256 threads ----
    const float4* cb4 = (const float4*)cb;
    float4* q4 = (float4*)q_out;
    const int rbase = blockIdx.x * ROWS_PER_BLOCK;
#pragma unroll
    for (int it = 0; it < 4; ++it) {
        const int slot = it * BLOCK + tid;   // 0..1023
        const int rl   = slot >> 4;          // row 0..63
        const int c4   = slot & 15;          // float4 column
        q4[(size_t)(rbase + rl) * 16 + c4] = cb4[s_idx[rl] * 16 + c4];
    }
}

extern "C" void kernel_launch(void* const* d_in, const int* in_sizes, int n_in,
                              void* d_out, int out_size, void* d_ws, size_t ws_size,
                              hipStream_t stream) {
    const float* h  = (const float*)d_in[0];
    const float* cb = (const float*)d_in[1];
    float* out   = (float*)d_out;
    float* z_out = out;              // 131072 floats
    float* q_out = out + N_ROWS;     // 131072*64 floats
    float* c2    = (float*)d_ws;     // 1024 floats

    c2_kernel<<<dim3(KCODES / 256), dim3(256), 0, stream>>>(cb, c2);
    vq_argmin_kernel<<<dim3(N_ROWS / ROWS_PER_BLOCK), dim3(BLOCK), 0, stream>>>(
        h, cb, c2, z_out, q_out);
}

// Round 6
// 388.609 us; speedup vs baseline: 3.0851x; 3.0851x over previous
//
#include <hip/hip_runtime.h>

#define N_ROWS 131072
#define KCODES 1024
#define DIM 64
#define BLOCK 256
#define NSEG 2
#define SEGK (KCODES / NSEG)   // 512 codes per segment

// h: [32, 64, 64, 64] fp32 (B, D, H, W) -> row n = b*4096 + y*64 + x reads h[b][d][y][x]
// codebook: [1024, 64] fp32
// out: [131072] z-as-float ++ [131072*64] q fp32
// d_ws: c2[1024] f32 | pd[2][131072] f32 | pk[2][131072] i32   (~2.004 MB)

// ---- kernel 1: c2[k] = ||codebook[k]||^2, numpy-pairwise order ----
__global__ void c2_kernel(const float* __restrict__ cb, float* __restrict__ c2)
{
#pragma clang fp contract(off)
    const int k = blockIdx.x * 256 + threadIdx.x;
    const float* c = cb + k * DIM;
    float r0 = c[0]*c[0], r1 = c[1]*c[1], r2 = c[2]*c[2], r3 = c[3]*c[3];
    float r4 = c[4]*c[4], r5 = c[5]*c[5], r6 = c[6]*c[6], r7 = c[7]*c[7];
#pragma unroll
    for (int i = 1; i < 8; ++i) {
        r0 = r0 + c[i*8+0]*c[i*8+0];
        r1 = r1 + c[i*8+1]*c[i*8+1];
        r2 = r2 + c[i*8+2]*c[i*8+2];
        r3 = r3 + c[i*8+3]*c[i*8+3];
        r4 = r4 + c[i*8+4]*c[i*8+4];
        r5 = r5 + c[i*8+5]*c[i*8+5];
        r6 = r6 + c[i*8+6]*c[i*8+6];
        r7 = r7 + c[i*8+7]*c[i*8+7];
    }
    c2[k] = ((r0 + r1) + (r2 + r3)) + ((r4 + r5) + (r6 + r7));
}

// ---- kernel 2: partial argmin over a block-uniform 512-code segment ----
// grid (512, NSEG); blockIdx.y = segment -> SGPR-uniform -> s_load codebook stream
__global__ void
__attribute__((amdgpu_flat_work_group_size(256, 256), amdgpu_waves_per_eu(4, 4)))
vq_partial_kernel(
    const float* __restrict__ h,
    const float* __restrict__ cb,
    const float* __restrict__ c2g,
    float* __restrict__ pd,
    int*   __restrict__ pk)
{
    __shared__ float s_c2[KCODES];

    const int tid   = threadIdx.x;
    const int row   = blockIdx.x * BLOCK + tid;
    const int kbase = (int)blockIdx.y * SEGK;     // block-uniform

    // c2 -> LDS, coalesced
#pragma unroll
    for (int i = 0; i < KCODES / BLOCK; ++i)
        s_c2[i * BLOCK + tid] = c2g[i * BLOCK + tid];
    __syncthreads();

    // ---- row x: 16 float4 pinned to VGPRs ----
    const int b  = row >> 12;
    const int yx = row & 4095;
    const float* hp = h + (size_t)b * (DIM * 4096) + yx;

#define LD(d) hp[(size_t)(d) * 4096]
#define XDECL(n) float4 x##n = make_float4(LD(4*(n)+0), LD(4*(n)+1), LD(4*(n)+2), LD(4*(n)+3)); \
    asm("" : "+v"(x##n.x), "+v"(x##n.y), "+v"(x##n.z), "+v"(x##n.w));
    XDECL(0)  XDECL(1)  XDECL(2)  XDECL(3)
    XDECL(4)  XDECL(5)  XDECL(6)  XDECL(7)
    XDECL(8)  XDECL(9)  XDECL(10) XDECL(11)
    XDECL(12) XDECL(13) XDECL(14) XDECL(15)
#undef XDECL
#undef LD

    // ---- S = ||x||^2, numpy pairwise (identical across segments) ----
    float S;
    {
#pragma clang fp contract(off)
        float r0 = x0.x*x0.x, r1 = x0.y*x0.y, r2 = x0.z*x0.z, r3 = x0.w*x0.w;
        float r4 = x1.x*x1.x, r5 = x1.y*x1.y, r6 = x1.z*x1.z, r7 = x1.w*x1.w;
#define SQACC(ve, vo) \
        r0 = r0 + ve.x*ve.x; r1 = r1 + ve.y*ve.y; r2 = r2 + ve.z*ve.z; r3 = r3 + ve.w*ve.w; \
        r4 = r4 + vo.x*vo.x; r5 = r5 + vo.y*vo.y; r6 = r6 + vo.z*vo.z; r7 = r7 + vo.w*vo.w;
        SQACC(x2,  x3)  SQACC(x4,  x5)  SQACC(x6,  x7)
        SQACC(x8,  x9)  SQACC(x10, x11) SQACC(x12, x13)
        SQACC(x14, x15)
#undef SQACC
        S = ((r0 + r1) + (r2 + r3)) + ((r4 + r5) + (r6 + r7));
    }

    // ---- scan 512 codes, 2/iter, sequential FMA chains (bit-exact d2) ----
    float best_d = 3.4e38f;
    int   best_k = kbase;

#define DOT4(v, base) \
        a0 = __builtin_fmaf(v.x, c0[(base)+0], a0); a1 = __builtin_fmaf(v.x, c1[(base)+0], a1); \
        a0 = __builtin_fmaf(v.y, c0[(base)+1], a0); a1 = __builtin_fmaf(v.y, c1[(base)+1], a1); \
        a0 = __builtin_fmaf(v.z, c0[(base)+2], a0); a1 = __builtin_fmaf(v.z, c1[(base)+2], a1); \
        a0 = __builtin_fmaf(v.w, c0[(base)+3], a0); a1 = __builtin_fmaf(v.w, c1[(base)+3], a1);

    for (int k = kbase; k < kbase + SEGK; k += 2) {
        const float* c0 = cb + (k << 6);   // block-uniform -> s_load stream
        const float* c1 = c0 + DIM;
        float a0 = 0.0f, a1 = 0.0f;
        DOT4(x0,  0)  DOT4(x1,  4)  DOT4(x2,  8)  DOT4(x3,  12)
        DOT4(x4,  16) DOT4(x5,  20) DOT4(x6,  24) DOT4(x7,  28)
        DOT4(x8,  32) DOT4(x9,  36) DOT4(x10, 40) DOT4(x11, 44)
        DOT4(x12, 48) DOT4(x13, 52) DOT4(x14, 56) DOT4(x15, 60)

        float d2a, d2b;
        {
#pragma clang fp contract(off)
            float ta = 2.0f * a0;     // exact
            float tb = 2.0f * a1;
            float ua = S - ta;        // rounded like np
            float ub = S - tb;
            d2a = ua + s_c2[k];
            d2b = ub + s_c2[k + 1];
        }
        if (d2a < best_d) { best_d = d2a; best_k = k; }
        if (d2b < best_d) { best_d = d2b; best_k = k + 1; }
    }
#undef DOT4

    pd[(size_t)blockIdx.y * N_ROWS + row] = best_d;
    pk[(size_t)blockIdx.y * N_ROWS + row] = best_k;
}

// ---- kernel 3: merge segments (seg order + strict < = np first-index) + q gather ----
__global__ void vq_combine_kernel(
    const float* __restrict__ pd,
    const int*   __restrict__ pk,
    const float* __restrict__ cb,
    float* __restrict__ z_out,
    float* __restrict__ q_out)
{
    __shared__ int s_idx[BLOCK];
    const int tid = threadIdx.x;
    const int row = blockIdx.x * BLOCK + tid;

    float bd = pd[row];
    int   bk = pk[row];
#pragma unroll
    for (int s = 1; s < NSEG; ++s) {
        float d = pd[(size_t)s * N_ROWS + row];
        int   k = pk[(size_t)s * N_ROWS + row];
        if (d < bd) { bd = d; bk = k; }
    }
    z_out[row] = (float)bk;
    s_idx[tid] = bk;
    __syncthreads();

    // cooperative q gather: bit-exact codebook rows, coalesced float4 stores
    const int lane16 = tid & 15;
    const int rsub   = tid >> 4;
    const float4* cb4 = (const float4*)cb;
    float4* q4 = (float4*)q_out;
    const int row_base = blockIdx.x * BLOCK;
#pragma unroll
    for (int it = 0; it < 16; ++it) {
        const int rl  = it * 16 + rsub;
        const int idx = s_idx[rl];
        q4[(size_t)(row_base + rl) * 16 + lane16] = cb4[idx * 16 + lane16];
    }
}

extern "C" void kernel_launch(void* const* d_in, const int* in_sizes, int n_in,
                              void* d_out, int out_size, void* d_ws, size_t ws_size,
                              hipStream_t stream) {
    const float* h  = (const float*)d_in[0];
    const float* cb = (const float*)d_in[1];
    float* out   = (float*)d_out;
    float* z_out = out;              // 131072 floats
    float* q_out = out + N_ROWS;     // 131072*64 floats

    char* ws = (char*)d_ws;
    float* c2 = (float*)ws;                                   // 4 KB
    float* pd = (float*)(ws + 4096);                          // NSEG*N_ROWS*4 = 1 MB
    int*   pk = (int*)(ws + 4096 + NSEG * N_ROWS * 4);        // 1 MB

    c2_kernel<<<dim3(KCODES / 256), dim3(256), 0, stream>>>(cb, c2);
    vq_partial_kernel<<<dim3(N_ROWS / BLOCK, NSEG), dim3(BLOCK), 0, stream>>>(
        h, cb, c2, pd, pk);
    vq_combine_kernel<<<dim3(N_ROWS / BLOCK), dim3(BLOCK), 0, stream>>>(
        pd, pk, cb, z_out, q_out);
}

// Round 9
// 349.254 us; speedup vs baseline: 3.4327x; 1.1127x over previous
//
#include <hip/hip_runtime.h>

#define N_ROWS 131072
#define KCODES 1024
#define DIM 64
#define BLOCK 256
#define ROWS_PB 64
#define KCHUNK 128
#define NCHUNK (KCODES / KCHUNK)
#define XSTR 68   // floats/row in LDS: 16B-aligned, ri-stride 68%32=4 banks -> 2-way (free)
#define CSTR 68

// h: [32, 64, 64, 64] fp32 (B, D, H, W); codebook: [1024, 64] fp32
// out: z[131072] as float ++ q[131072*64] fp32 ; d_ws: UNUSED (harness poison-races on it)

__global__ __launch_bounds__(BLOCK, 2) void vq_main(
    const float* __restrict__ h,
    const float* __restrict__ cb,
    float* __restrict__ z_out,
    float* __restrict__ q_out)
{
    __shared__ float xs[ROWS_PB * XSTR];   // 17408 B
    __shared__ float cs[KCHUNK * CSTR];    // 34816 B (reused as merge arrays)
    __shared__ float ss[ROWS_PB];
    __shared__ float cc2[KCHUNK];
    __shared__ int   s_idx[ROWS_PB];

    const int tid  = threadIdx.x;
    const int row0 = blockIdx.x * ROWS_PB;
    const int bb   = row0 >> 12;           // 4096 rows per batch image
    const int yx0  = row0 & 4095;

    // ---- stage x tile: xs[rl][d], coalesced global reads ----
    {
        const int rl = tid & 63;
        const int dg = tid >> 6;           // 0..3
        const float* hb = h + (size_t)bb * (DIM * 4096) + yx0 + rl;
#pragma unroll
        for (int it = 0; it < 16; ++it) {
            const int d = it * 4 + dg;
            xs[rl * XSTR + d] = hb[(size_t)d * 4096];
        }
    }
    __syncthreads();

    // ---- S[r] = ||x_r||^2, numpy pairwise (8 strided accumulators) ----
    if (tid < ROWS_PB) {
#pragma clang fp contract(off)
        const float* xr = &xs[tid * XSTR];
        float r0 = xr[0]*xr[0], r1 = xr[1]*xr[1], r2 = xr[2]*xr[2], r3 = xr[3]*xr[3];
        float r4 = xr[4]*xr[4], r5 = xr[5]*xr[5], r6 = xr[6]*xr[6], r7 = xr[7]*xr[7];
#pragma unroll
        for (int i = 1; i < 8; ++i) {
            r0 = r0 + xr[i*8+0]*xr[i*8+0];
            r1 = r1 + xr[i*8+1]*xr[i*8+1];
            r2 = r2 + xr[i*8+2]*xr[i*8+2];
            r3 = r3 + xr[i*8+3]*xr[i*8+3];
            r4 = r4 + xr[i*8+4]*xr[i*8+4];
            r5 = r5 + xr[i*8+5]*xr[i*8+5];
            r6 = r6 + xr[i*8+6]*xr[i*8+6];
            r7 = r7 + xr[i*8+7]*xr[i*8+7];
        }
        ss[tid] = ((r0 + r1) + (r2 + r3)) + ((r4 + r5) + (r6 + r7));
    }
    __syncthreads();

    // thread tile: rows {rr*16+ri}, codes per chunk {wv*32 + j*4 + ci}
    const int wv   = tid >> 6;
    const int lane = tid & 63;
    const int ri   = lane >> 2;            // 0..15
    const int ci   = lane & 3;             // 0..3

    const float S0 = ss[ 0 + ri];
    const float S1 = ss[16 + ri];
    const float S2 = ss[32 + ri];
    const float S3 = ss[48 + ri];

    float bd0 = 3.4e38f, bd1 = 3.4e38f, bd2 = 3.4e38f, bd3 = 3.4e38f;
    int   bk0 = 0, bk1 = 0, bk2 = 0, bk3 = 0;
    const int kl0 = wv * 32 + ci;          // thread code base (+ j*4)

    for (int kc = 0; kc < NCHUNK; ++kc) {
        __syncthreads();                   // cs reuse guard
        {
            const float4* g4 = (const float4*)(cb + kc * KCHUNK * DIM);
#pragma unroll
            for (int i = 0; i < 8; ++i) {
                const int g    = i * BLOCK + tid;   // float4 index 0..2047
                const int code = g >> 4;
                const int col  = g & 15;
                *(float4*)&cs[code * CSTR + col * 4] = g4[g];
            }
        }
        __syncthreads();

        // cc2[kl] = ||code||^2 from staged cs — identical pairwise order, bit-exact
        if (tid < KCHUNK) {
#pragma clang fp contract(off)
            const float* c = &cs[tid * CSTR];
            float r0 = c[0]*c[0], r1 = c[1]*c[1], r2 = c[2]*c[2], r3 = c[3]*c[3];
            float r4 = c[4]*c[4], r5 = c[5]*c[5], r6 = c[6]*c[6], r7 = c[7]*c[7];
#pragma unroll
            for (int i = 1; i < 8; ++i) {
                r0 = r0 + c[i*8+0]*c[i*8+0];
                r1 = r1 + c[i*8+1]*c[i*8+1];
                r2 = r2 + c[i*8+2]*c[i*8+2];
                r3 = r3 + c[i*8+3]*c[i*8+3];
                r4 = r4 + c[i*8+4]*c[i*8+4];
                r5 = r5 + c[i*8+5]*c[i*8+5];
                r6 = r6 + c[i*8+6]*c[i*8+6];
                r7 = r7 + c[i*8+7]*c[i*8+7];
            }
            cc2[tid] = ((r0 + r1) + (r2 + r3)) + ((r4 + r5) + (r6 + r7));
        }
        __syncthreads();

        float acc[4][8];
#pragma unroll
        for (int rr = 0; rr < 4; ++rr)
#pragma unroll
            for (int j = 0; j < 8; ++j) acc[rr][j] = 0.0f;

#pragma unroll
        for (int dc = 0; dc < 16; ++dc) {
            const int d = dc * 4;
            const float4 xf0 = *(const float4*)&xs[( 0 + ri) * XSTR + d];
            const float4 xf1 = *(const float4*)&xs[(16 + ri) * XSTR + d];
            const float4 xf2 = *(const float4*)&xs[(32 + ri) * XSTR + d];
            const float4 xf3 = *(const float4*)&xs[(48 + ri) * XSTR + d];
#pragma unroll
            for (int j = 0; j < 8; ++j) {
                const float4 cf = *(const float4*)&cs[(kl0 + j * 4) * CSTR + d];
                acc[0][j] = __builtin_fmaf(xf0.x, cf.x, acc[0][j]);
                acc[0][j] = __builtin_fmaf(xf0.y, cf.y, acc[0][j]);
                acc[0][j] = __builtin_fmaf(xf0.z, cf.z, acc[0][j]);
                acc[0][j] = __builtin_fmaf(xf0.w, cf.w, acc[0][j]);
                acc[1][j] = __builtin_fmaf(xf1.x, cf.x, acc[1][j]);
                acc[1][j] = __builtin_fmaf(xf1.y, cf.y, acc[1][j]);
                acc[1][j] = __builtin_fmaf(xf1.z, cf.z, acc[1][j]);
                acc[1][j] = __builtin_fmaf(xf1.w, cf.w, acc[1][j]);
                acc[2][j] = __builtin_fmaf(xf2.x, cf.x, acc[2][j]);
                acc[2][j] = __builtin_fmaf(xf2.y, cf.y, acc[2][j]);
                acc[2][j] = __builtin_fmaf(xf2.z, cf.z, acc[2][j]);
                acc[2][j] = __builtin_fmaf(xf2.w, cf.w, acc[2][j]);
                acc[3][j] = __builtin_fmaf(xf3.x, cf.x, acc[3][j]);
                acc[3][j] = __builtin_fmaf(xf3.y, cf.y, acc[3][j]);
                acc[3][j] = __builtin_fmaf(xf3.z, cf.z, acc[3][j]);
                acc[3][j] = __builtin_fmaf(xf3.w, cf.w, acc[3][j]);
            }
        }

        // chunk epilogue: exact d2 + argmin update, j ascending = k ascending
#pragma unroll
        for (int j = 0; j < 8; ++j) {
            {
#pragma clang fp contract(off)
                const int kl  = kl0 + j * 4;
                const int k   = kc * KCHUNK + kl;
                const float c2v = cc2[kl];
                float t0 = 2.0f * acc[0][j]; float u0 = S0 - t0; float d20 = u0 + c2v;
                float t1 = 2.0f * acc[1][j]; float u1 = S1 - t1; float d21 = u1 + c2v;
                float t2 = 2.0f * acc[2][j]; float u2 = S2 - t2; float d22 = u2 + c2v;
                float t3 = 2.0f * acc[3][j]; float u3 = S3 - t3; float d23 = u3 + c2v;
                if (d20 < bd0) { bd0 = d20; bk0 = k; }
                if (d21 < bd1) { bd1 = d21; bk1 = k; }
                if (d22 < bd2) { bd2 = d22; bk2 = k; }
                if (d23 < bd3) { bd3 = d23; bk3 = k; }
            }
        }
    }

    // ---- merge: per-row lex-min over 16 slots (d,k) = np first-index ----
    __syncthreads();
    float* sbd = cs;                        // [64][16]
    int*   sbk = (int*)(cs + ROWS_PB * 16); // [64][16]
    const int slot = wv * 4 + ci;
    sbd[( 0 + ri) * 16 + slot] = bd0;  sbk[( 0 + ri) * 16 + slot] = bk0;
    sbd[(16 + ri) * 16 + slot] = bd1;  sbk[(16 + ri) * 16 + slot] = bk1;
    sbd[(32 + ri) * 16 + slot] = bd2;  sbk[(32 + ri) * 16 + slot] = bk2;
    sbd[(48 + ri) * 16 + slot] = bd3;  sbk[(48 + ri) * 16 + slot] = bk3;
    __syncthreads();

    if (tid < ROWS_PB) {
        float bd = sbd[tid * 16];
        int   bk = sbk[tid * 16];
#pragma unroll
        for (int s = 1; s < 16; ++s) {
            const float d = sbd[tid * 16 + s];
            const int   k = sbk[tid * 16 + s];
            if (d < bd || (d == bd && k < bk)) { bd = d; bk = k; }
        }
        z_out[row0 + tid] = (float)bk;
        s_idx[tid] = bk;
    }
    __syncthreads();

    // ---- q gather: bit-exact codebook rows, coalesced float4 stores ----
    const int lane16 = tid & 15;
    const int rsub   = tid >> 4;
    const float4* cb4 = (const float4*)cb;
    float4* q4 = (float4*)q_out;
#pragma unroll
    for (int it = 0; it < 4; ++it) {
        const int rl = it * 16 + rsub;
        q4[(size_t)(row0 + rl) * 16 + lane16] = cb4[s_idx[rl] * 16 + lane16];
    }
}

extern "C" void kernel_launch(void* const* d_in, const int* in_sizes, int n_in,
                              void* d_out, int out_size, void* d_ws, size_t ws_size,
                              hipStream_t stream) {
    const float* h  = (const float*)d_in[0];
    const float* cb = (const float*)d_in[1];
    float* out   = (float*)d_out;
    float* z_out = out;              // 131072 floats
    float* q_out = out + N_ROWS;     // 131072*64 floats
    (void)d_ws; (void)ws_size;       // intentionally unused

    vq_main<<<dim3(N_ROWS / ROWS_PB), dim3(BLOCK), 0, stream>>>(h, cb, z_out, q_out);
}

// Round 10
// 319.189 us; speedup vs baseline: 3.7561x; 1.0942x over previous
//
#include <hip/hip_runtime.h>

#define N_ROWS 131072
#define KCODES 1024
#define DIM 64
#define BLOCK 256
#define ROWS_PB 128
#define KCHUNK 128
#define NCHUNK (KCODES / KCHUNK)

// padded LDS row offset: row stride 68 floats + 4-float pad every 8 rows.
// -> within an 8-row group: stride 68 (j*272B, 16B aligned)
// -> 8-row group stride 548 = 4 mod 32 banks: xs (4 groups/wave) hit disjoint
//    bank-quads; cs (16 groups/wave) alias 2-way (free per m136).
__device__ __forceinline__ int POFF(int r) { return r * 68 + (r >> 3) * 4; }

// h: [32, 64, 64, 64] fp32 (B, D, H, W); codebook: [1024, 64] fp32
// out: z[131072] as float ++ q[131072*64] fp32 ; d_ws unused

__global__ void
__attribute__((amdgpu_flat_work_group_size(256, 256), amdgpu_waves_per_eu(2, 2)))
vq_main(const float* __restrict__ h,
        const float* __restrict__ cb,
        float* __restrict__ z_out,
        float* __restrict__ q_out)
{
    __shared__ float xs[8760];        // 128 rows, padded      (35040 B)
    __shared__ float cs[8760];        // 128 codes, padded     (35040 B, reused for merge)
    __shared__ float s_c2[KCODES];    // 4096 B
    __shared__ float ss[ROWS_PB];     // 512 B
    __shared__ int   s_idx[ROWS_PB];  // 512 B

    const int tid  = threadIdx.x;
    const int row0 = blockIdx.x * ROWS_PB;
    const int bb   = row0 >> 12;
    const int yx0  = row0 & 4095;

    // ---- stage x tile (coalesced: lanes = consecutive rows) ----
    {
        const int rl = tid & 127;
        const int dg = tid >> 7;              // 0..1
        const float* hb = h + (size_t)bb * (DIM * 4096) + yx0 + rl;
        const int xo = POFF(rl);
#pragma unroll
        for (int t = 0; t < 32; ++t) {
            const int d = t * 2 + dg;
            xs[xo + d] = hb[(size_t)d * 4096];
        }
    }

    // ---- s_c2 for ALL codes, once, from global (bit-identical pairwise formula) ----
    {
#pragma clang fp contract(off)
#pragma unroll
        for (int cc = 0; cc < 4; ++cc) {
            const int code = cc * BLOCK + tid;
            const float* c = cb + code * DIM;
            float r0 = c[0]*c[0], r1 = c[1]*c[1], r2 = c[2]*c[2], r3 = c[3]*c[3];
            float r4 = c[4]*c[4], r5 = c[5]*c[5], r6 = c[6]*c[6], r7 = c[7]*c[7];
#pragma unroll
            for (int i = 1; i < 8; ++i) {
                r0 = r0 + c[i*8+0]*c[i*8+0];
                r1 = r1 + c[i*8+1]*c[i*8+1];
                r2 = r2 + c[i*8+2]*c[i*8+2];
                r3 = r3 + c[i*8+3]*c[i*8+3];
                r4 = r4 + c[i*8+4]*c[i*8+4];
                r5 = r5 + c[i*8+5]*c[i*8+5];
                r6 = r6 + c[i*8+6]*c[i*8+6];
                r7 = r7 + c[i*8+7]*c[i*8+7];
            }
            s_c2[code] = ((r0 + r1) + (r2 + r3)) + ((r4 + r5) + (r6 + r7));
        }
    }
    __syncthreads();

    // ---- S[r] = ||x_r||^2 from staged xs (same bits as global) ----
    if (tid < ROWS_PB) {
#pragma clang fp contract(off)
        const float* xr = &xs[POFF(tid)];
        float r0 = xr[0]*xr[0], r1 = xr[1]*xr[1], r2 = xr[2]*xr[2], r3 = xr[3]*xr[3];
        float r4 = xr[4]*xr[4], r5 = xr[5]*xr[5], r6 = xr[6]*xr[6], r7 = xr[7]*xr[7];
#pragma unroll
        for (int i = 1; i < 8; ++i) {
            r0 = r0 + xr[i*8+0]*xr[i*8+0];
            r1 = r1 + xr[i*8+1]*xr[i*8+1];
            r2 = r2 + xr[i*8+2]*xr[i*8+2];
            r3 = r3 + xr[i*8+3]*xr[i*8+3];
            r4 = r4 + xr[i*8+4]*xr[i*8+4];
            r5 = r5 + xr[i*8+5]*xr[i*8+5];
            r6 = r6 + xr[i*8+6]*xr[i*8+6];
            r7 = r7 + xr[i*8+7]*xr[i*8+7];
        }
        ss[tid] = ((r0 + r1) + (r2 + r3)) + ((r4 + r5) + (r6 + r7));
    }
    __syncthreads();

    // thread tile: 8 rows (rg*8+rr) x 8 codes (cg*8+j)
    const int rg = tid >> 4;          // 0..15
    const int cg = tid & 15;          // 0..15
    const float* xb = &xs[POFF(rg * 8)];   // row rr at +68*rr (no pad inside group)
    const float* cbse = &cs[POFF(cg * 8)]; // code j at +68*j

    float Sv[8];
#pragma unroll
    for (int rr = 0; rr < 8; ++rr) Sv[rr] = ss[rg * 8 + rr];

    float bd[8];
    int   bk[8];
#pragma unroll
    for (int rr = 0; rr < 8; ++rr) { bd[rr] = 3.4e38f; bk[rr] = 0; }

    for (int kc = 0; kc < NCHUNK; ++kc) {
        __syncthreads();                   // cs reuse guard
        {
            const float4* g4 = (const float4*)(cb + kc * KCHUNK * DIM);
#pragma unroll
            for (int i = 0; i < 8; ++i) {
                const int g    = i * BLOCK + tid;   // 0..2047
                const int code = g >> 4;
                const int col  = g & 15;
                *(float4*)&cs[POFF(code) + col * 4] = g4[g];
            }
        }
        __syncthreads();

        float acc[8][8];
#pragma unroll
        for (int rr = 0; rr < 8; ++rr)
#pragma unroll
            for (int j = 0; j < 8; ++j) acc[rr][j] = 0.0f;

#pragma unroll 1
        for (int dc = 0; dc < 16; ++dc) {
            const int d = dc * 4;
            float4 cf[8];
#pragma unroll
            for (int j = 0; j < 8; ++j)
                cf[j] = *(const float4*)&cbse[68 * j + d];
#pragma unroll
            for (int rr = 0; rr < 8; ++rr) {
                const float4 xf = *(const float4*)&xb[68 * rr + d];
#pragma unroll
                for (int j = 0; j < 8; ++j) {
                    acc[rr][j] = __builtin_fmaf(xf.x, cf[j].x, acc[rr][j]);
                    acc[rr][j] = __builtin_fmaf(xf.y, cf[j].y, acc[rr][j]);
                    acc[rr][j] = __builtin_fmaf(xf.z, cf[j].z, acc[rr][j]);
                    acc[rr][j] = __builtin_fmaf(xf.w, cf[j].w, acc[rr][j]);
                }
            }
        }

        // chunk epilogue: exact d2 + argmin, j ascending = k ascending
#pragma unroll
        for (int j = 0; j < 8; ++j) {
            {
#pragma clang fp contract(off)
                const int k     = kc * KCHUNK + cg * 8 + j;
                const float c2v = s_c2[k];
#pragma unroll
                for (int rr = 0; rr < 8; ++rr) {
                    float t  = 2.0f * acc[rr][j];   // exact
                    float u  = Sv[rr] - t;          // rounded like np
                    float d2 = u + c2v;
                    if (d2 < bd[rr]) { bd[rr] = d2; bk[rr] = k; }
                }
            }
        }
    }

    // ---- merge: per-row lex-min over 16 cg slots (d,k) = np first-index ----
    __syncthreads();
    float* sbd = cs;                          // [128][16]
    int*   sbk = (int*)(cs + ROWS_PB * 16);   // [128][16]
#pragma unroll
    for (int rr = 0; rr < 8; ++rr) {
        sbd[(rg * 8 + rr) * 16 + cg] = bd[rr];
        sbk[(rg * 8 + rr) * 16 + cg] = bk[rr];
    }
    __syncthreads();

    if (tid < ROWS_PB) {
        float fb = sbd[tid * 16];
        int   fk = sbk[tid * 16];
#pragma unroll
        for (int s = 1; s < 16; ++s) {
            const float d = sbd[tid * 16 + s];
            const int   k = sbk[tid * 16 + s];
            if (d < fb || (d == fb && k < fk)) { fb = d; fk = k; }
        }
        z_out[row0 + tid] = (float)fk;
        s_idx[tid] = fk;
    }
    __syncthreads();

    // ---- q gather: bit-exact codebook rows, coalesced float4 stores ----
    const float4* cb4 = (const float4*)cb;
    float4* q4 = (float4*)q_out;
#pragma unroll
    for (int it = 0; it < 8; ++it) {
        const int slot = it * BLOCK + tid;    // 0..2047
        const int rl   = slot >> 4;           // row 0..127
        const int c4   = slot & 15;
        q4[(size_t)(row0 + rl) * 16 + c4] = cb4[s_idx[rl] * 16 + c4];
    }
}

extern "C" void kernel_launch(void* const* d_in, const int* in_sizes, int n_in,
                              void* d_out, int out_size, void* d_ws, size_t ws_size,
                              hipStream_t stream) {
    const float* h  = (const float*)d_in[0];
    const float* cb = (const float*)d_in[1];
    float* out   = (float*)d_out;
    float* z_out = out;              // 131072 floats
    float* q_out = out + N_ROWS;     // 131072*64 floats
    (void)d_ws; (void)ws_size;

    vq_main<<<dim3(N_ROWS / ROWS_PB), dim3(BLOCK), 0, stream>>>(h, cb, z_out, q_out);
}